// Round 5
// baseline (143.217 us; speedup 1.0000x reference)
//
#include <hip/hip_runtime.h>
#include <stdint.h>

// Problem constants: B=4, T=2048, C=512, H=8, D=64
typedef __attribute__((ext_vector_type(8))) __bf16 bf16x8;
typedef __attribute__((ext_vector_type(4))) __bf16 bf16x4;
typedef __attribute__((ext_vector_type(2))) __bf16 bf16x2;
typedef __attribute__((ext_vector_type(4))) float f32x4;
typedef __attribute__((ext_vector_type(16))) float f32x16;
typedef __attribute__((ext_vector_type(4))) unsigned u32x4;
typedef __attribute__((ext_vector_type(2))) int i32x2;

__device__ __forceinline__ unsigned short f2bf(float f) {
  unsigned u = __float_as_uint(f);
  u += 0x7FFFu + ((u >> 16) & 1u);   // round-to-nearest-even
  return (unsigned short)(u >> 16);
}

__device__ __forceinline__ float exp2fast(float x) {
#if __has_builtin(__builtin_amdgcn_exp2f)
  return __builtin_amdgcn_exp2f(x);
#else
  return __expf(x * 0.6931471805599453f);
#endif
}

__device__ __forceinline__ void pl32swap(unsigned &a, unsigned &b) {
#if __has_builtin(__builtin_amdgcn_permlane32_swap)
  i32x2 r = __builtin_amdgcn_permlane32_swap((int)a, (int)b, false, false);
  a = (unsigned)r[0]; b = (unsigned)r[1];
#else
  asm volatile("v_permlane32_swap_b32 %0, %1" : "+v"(a), "+v"(b));
#endif
}

// rows r, r+8, r+16, r+24 get distinct octets (was 4-way conflicted with r&7)
__device__ __forceinline__ int swz8(int r) { return (r & 7) ^ ((r >> 3) & 3); }

__device__ __forceinline__ void gload16(const unsigned short* src, unsigned short* ldsdst) {
  __builtin_amdgcn_global_load_lds(
      (const __attribute__((address_space(1))) unsigned int*)src,
      (__attribute__((address_space(3))) unsigned int*)ldsdst, 16, 0, 0);
}

// Stage 8 rows x 64 bf16 (128B/row) into LDS tile (linear dest), with the
// global-source octet XOR-swizzled by swz8(row) so swizzled reads are
// bank-conflict-free (G21: swizzle source+read, dest stays linear).
__device__ __forceinline__ void stage8(const unsigned short* gbase, long long strideElems,
                                       unsigned short* ldsTile, int rowBase) {
  const int lane = threadIdx.x & 63;
  const int r = rowBase + (lane >> 3);
  const int oct = (lane & 7) ^ swz8(r);
  gload16(gbase + (long long)r * strideElems + oct * 8, ldsTile + rowBase * 64);
}

// ---------------- merged prep kernel ----------------

__global__ __launch_bounds__(256) void prep(const float* __restrict__ x,
                                            unsigned short* __restrict__ xb,
                                            const float* __restrict__ wq,
                                            unsigned short* __restrict__ wqt,
                                            const float* __restrict__ wp,
                                            unsigned short* __restrict__ wpt,
                                            const int* __restrict__ adj,
                                            unsigned long long* __restrict__ mb) {
  int blk = blockIdx.x;
  if (blk < 16384) {
    int tid = blk * 256 + threadIdx.x;
    int4 v = ((const int4*)adj)[tid];
    unsigned n = (v.x != 0 ? 1u : 0u) | (v.y != 0 ? 2u : 0u) |
                 (v.z != 0 ? 4u : 0u) | (v.w != 0 ? 8u : 0u);
    unsigned long long part = (unsigned long long)n << ((threadIdx.x & 15) * 4);
    part |= __shfl_xor(part, 1);
    part |= __shfl_xor(part, 2);
    part |= __shfl_xor(part, 4);
    part |= __shfl_xor(part, 8);
    if ((threadIdx.x & 15) == 0) mb[tid >> 4] = part;
    return;
  }
  blk -= 16384;
  if (blk < 4096) {
    int i = (blk * 256 + threadIdx.x) * 4;
    float4 v = *(const float4*)(x + i);
    ushort4 o;
    o.x = f2bf(v.x); o.y = f2bf(v.y); o.z = f2bf(v.z); o.w = f2bf(v.w);
    *(ushort4*)(xb + i) = o;
    return;
  }
  blk -= 4096;
  const float* w; unsigned short* wt; int N; int bx, by;
  if (blk < 768) { w = wq; wt = wqt; N = 1536; bx = blk & 15; by = blk >> 4; }
  else { blk -= 768; w = wp; wt = wpt; N = 512; bx = blk & 15; by = blk >> 4; }
  __shared__ float tile[32][33];
  int k0 = bx * 32, n0 = by * 32;
  int tx = threadIdx.x & 31, ty = threadIdx.x >> 5;
#pragma unroll
  for (int i = 0; i < 4; i++)
    tile[ty + i * 8][tx] = w[(long long)(k0 + ty + i * 8) * N + n0 + tx];
  __syncthreads();
#pragma unroll
  for (int i = 0; i < 4; i++)
    wt[(long long)(n0 + ty + i * 8) * 512 + k0 + tx] = f2bf(tile[tx][ty + i * 8]);
}

// ---------------- GEMM core: C[128x128] = A[M,512] * Wt[N,512]^T ----------------

__device__ __forceinline__ void gemm_core(const unsigned short* __restrict__ A,
                                          const unsigned short* __restrict__ Wt,
                                          unsigned short (*Al)[128 * 64],
                                          unsigned short (*Bl)[128 * 64],
                                          int m0, int n0, f32x4 acc[4][4]) {
  const int lane = threadIdx.x & 63;
  const int wid = threadIdx.x >> 6;
  const int c = lane & 15, g = lane >> 4;
  const int wm = wid >> 1, wn = wid & 1;
  const unsigned short* Ab = A + (long long)m0 * 512;
  const unsigned short* Bb = Wt + (long long)n0 * 512;

#pragma unroll
  for (int i = 0; i < 4; i++) stage8(Ab, 512, Al[0], wid * 32 + i * 8);
#pragma unroll
  for (int i = 0; i < 4; i++) stage8(Bb, 512, Bl[0], wid * 32 + i * 8);
  asm volatile("s_waitcnt vmcnt(0)" ::: "memory");
  __syncthreads();

  int cur = 0;
  for (int k0 = 0; k0 < 512; k0 += 64) {
    if (k0 + 64 < 512) {
#pragma unroll
      for (int i = 0; i < 4; i++) stage8(Ab + k0 + 64, 512, Al[cur ^ 1], wid * 32 + i * 8);
#pragma unroll
      for (int i = 0; i < 4; i++) stage8(Bb + k0 + 64, 512, Bl[cur ^ 1], wid * 32 + i * 8);
    }
#pragma unroll
    for (int kk = 0; kk < 2; kk++) {
      bf16x8 af[4], bfr[4];
#pragma unroll
      for (int mi = 0; mi < 4; mi++) {
        int row = wm * 64 + mi * 16 + c;
        af[mi] = *(const bf16x8*)&Al[cur][row * 64 + (((kk << 2) | g) ^ swz8(row)) * 8];
      }
#pragma unroll
      for (int ni = 0; ni < 4; ni++) {
        int row = wn * 64 + ni * 16 + c;
        bfr[ni] = *(const bf16x8*)&Bl[cur][row * 64 + (((kk << 2) | g) ^ swz8(row)) * 8];
      }
#pragma unroll
      for (int mi = 0; mi < 4; mi++)
#pragma unroll
        for (int ni = 0; ni < 4; ni++)
          acc[mi][ni] = __builtin_amdgcn_mfma_f32_16x16x32_bf16(af[mi], bfr[ni], acc[mi][ni], 0, 0, 0);
    }
    asm volatile("s_waitcnt vmcnt(0)" ::: "memory");
    __syncthreads();
    cur ^= 1;
  }
}

__global__ __launch_bounds__(256) void gemm_qkv(const unsigned short* __restrict__ xb,
                                                const unsigned short* __restrict__ wqt,
                                                const float* __restrict__ bqkv,
                                                unsigned short* __restrict__ qb,
                                                unsigned short* __restrict__ kb,
                                                unsigned short* __restrict__ vtb) {
  __shared__ __align__(16) unsigned short Al[2][128 * 64];
  __shared__ __align__(16) unsigned short Bl[2][128 * 64];
  f32x4 acc[4][4] = {};
  int m0 = blockIdx.x * 128, n0 = blockIdx.y * 128;
  gemm_core(xb, wqt, Al, Bl, m0, n0, acc);
  const int lane = threadIdx.x & 63;
  const int wid = threadIdx.x >> 6;
  const int c = lane & 15, g = lane >> 4;
  const int wm = wid >> 1, wn = wid & 1;
#pragma unroll
  for (int ni = 0; ni < 4; ni++) {
    int n = n0 + wn * 64 + ni * 16 + c;
    float bv = bqkv[n];
    int which = n >> 9;
    int h = (n & 511) >> 6, d = n & 63;
#pragma unroll
    for (int mi = 0; mi < 4; mi++) {
      int mbase = m0 + wm * 64 + mi * 16 + g * 4;
#pragma unroll
      for (int j = 0; j < 4; j++) {
        int m = mbase + j;
        int b = m >> 11, t = m & 2047;
        int bh = b * 8 + h;
        float v = acc[mi][ni][j] + bv;
        if (which == 0)      qb[(bh * 2048 + t) * 64 + d] = f2bf(v * 0.18033688011112042f);
        else if (which == 1) kb[(bh * 2048 + t) * 64 + d] = f2bf(v);
        else                 vtb[(bh * 64 + d) * 2048 + t] = f2bf(v);
      }
    }
  }
}

__global__ __launch_bounds__(256) void gemm_proj(const unsigned short* __restrict__ yb,
                                                 const unsigned short* __restrict__ wpt,
                                                 const float* __restrict__ bproj,
                                                 float* __restrict__ out) {
  __shared__ __align__(16) unsigned short Al[2][128 * 64];
  __shared__ __align__(16) unsigned short Bl[2][128 * 64];
  f32x4 acc[4][4] = {};
  int m0 = blockIdx.x * 128, n0 = blockIdx.y * 128;
  gemm_core(yb, wpt, Al, Bl, m0, n0, acc);
  const int lane = threadIdx.x & 63;
  const int wid = threadIdx.x >> 6;
  const int c = lane & 15, g = lane >> 4;
  const int wm = wid >> 1, wn = wid & 1;
#pragma unroll
  for (int ni = 0; ni < 4; ni++) {
    int n = n0 + wn * 64 + ni * 16 + c;
    float bv = bproj[n];
#pragma unroll
    for (int mi = 0; mi < 4; mi++) {
      int mbase = m0 + wm * 64 + mi * 16 + g * 4;
#pragma unroll
      for (int j = 0; j < 4; j++)
        out[(long long)(mbase + j) * 512 + n] = acc[mi][ni][j] + bv;
    }
  }
}

// ---------------- flash attention, 32x32 MFMA, kv-split, register P ----------------
// Grid: 2048 1D blocks -> (bh = bid&31 [XCD-colocated], qblock, z = kv half).
// 2 waves x 32 q-rows, KV tile 64, K/V LDS double-buffered, mask as MFMA C-seed.
// No-max exp2 softmax => kv-split partials are additive: each block writes
// unnormalized f32 O^T partial + l partial; combine kernel finishes.
__global__ __launch_bounds__(128) void attn(const unsigned short* __restrict__ qb,
                                            const unsigned short* __restrict__ kb,
                                            const unsigned short* __restrict__ vtb,
                                            const unsigned long long* __restrict__ mbits,
                                            float* __restrict__ opart,
                                            float* __restrict__ lpart) {
  __shared__ __align__(16) unsigned short Kl[2][64 * 64];
  __shared__ __align__(16) unsigned short Vl[2][64 * 64];
  const int lane = threadIdx.x & 63;
  const int w = threadIdx.x >> 6;
  const int l31 = lane & 31, h5 = lane >> 5;
  const int sA = swz8(l31);            // same for row l31+32
  const int bid = blockIdx.x;
  const int bh = bid & 31;             // xcd = bid%8 = bh%8 -> K/V L2-resident
  const int tmp = bid >> 5;
  const int q0 = (tmp & 31) * 64;
  const int z = tmp >> 5;
  const int kvbase = z * 1024;
  const int b = bh >> 3, h = bh & 7;
  const int qglob = q0 + w * 32 + l31;

  const unsigned short* qptr = qb + ((long long)bh * 2048 + qglob) * 64;
  bf16x8 qf[4];
#pragma unroll
  for (int cc = 0; cc < 4; cc++) qf[cc] = *(const bf16x8*)(qptr + cc * 16 + h5 * 8);

  const unsigned long long* mrow = mbits + ((long long)b * 2048 + qglob) * 32 + z * 16;
  const unsigned short* kbase = kb + (long long)bh * 2048 * 64;
  const unsigned short* vbase = vtb + (long long)bh * 64 * 2048;

  f32x16 accO0 = {0,0,0,0, 0,0,0,0, 0,0,0,0, 0,0,0,0};
  f32x16 accO1 = {0,0,0,0, 0,0,0,0, 0,0,0,0, 0,0,0,0};
  float lrun = 0.0f;

  // prologue: stage tile 0 of this kv half
#pragma unroll
  for (int i = 0; i < 4; i++) stage8(kbase + (long long)kvbase * 64, 64, Kl[0], w * 32 + i * 8);
#pragma unroll
  for (int i = 0; i < 4; i++) stage8(vbase + kvbase, 2048, Vl[0], w * 32 + i * 8);
  unsigned long long mw = mrow[0];
  asm volatile("s_waitcnt vmcnt(0)" ::: "memory");
  __syncthreads();

  int cur = 0;
  for (int t = 0; t < 16; ++t) {
    unsigned long long mwn = 0;
    if (t < 15) {
      int kv0 = kvbase + (t + 1) * 64;
#pragma unroll
      for (int i = 0; i < 4; i++) stage8(kbase + (long long)kv0 * 64, 64, Kl[cur ^ 1], w * 32 + i * 8);
#pragma unroll
      for (int i = 0; i < 4; i++) stage8(vbase + kv0, 2048, Vl[cur ^ 1], w * 32 + i * 8);
      mwn = mrow[t + 1];
    }

    // ---- seed S^T accumulators with mask bias (0 / -1e30) ----
    // C reg r of tile ot: kv = ot*32 + (r&3) + 8*(r>>2) + 4*h5
    unsigned mh0 = ((unsigned)mw) >> (4 * h5);
    unsigned mh1 = ((unsigned)(mw >> 32)) >> (4 * h5);
    f32x16 st0, st1;
#pragma unroll
    for (int r = 0; r < 16; r++) {
      const int bi = (r & 3) + 8 * (r >> 2);
      st0[r] = ((mh0 >> bi) & 1u) ? 0.0f : -1e30f;
      st1[r] = ((mh1 >> bi) & 1u) ? 0.0f : -1e30f;
    }

    // ---- S^T = K * Q^T ----
    const unsigned short* Kb = &Kl[cur][0];
    const unsigned short* Vb = &Vl[cur][0];
    __builtin_amdgcn_s_setprio(1);
#pragma unroll
    for (int cc = 0; cc < 4; cc++) {
      int u = ((cc * 2 + h5) ^ sA) * 8;
      bf16x8 kf0 = *(const bf16x8*)&Kb[l31 * 64 + u];
      bf16x8 kf1 = *(const bf16x8*)&Kb[(32 + l31) * 64 + u];
      st0 = __builtin_amdgcn_mfma_f32_32x32x16_bf16(kf0, qf[cc], st0, 0, 0, 0);
      st1 = __builtin_amdgcn_mfma_f32_32x32x16_bf16(kf1, qf[cc], st1, 0, 0, 0);
    }
    __builtin_amdgcn_s_setprio(0);

    // ---- exp2 softmax (masked entries hit exp2(-1e30) = 0), pack bf16 ----
    unsigned pd[2][8];
    float lsum = 0.0f;
#pragma unroll
    for (int m = 0; m < 8; m++) {
      const int r0 = 2 * m, r1 = 2 * m + 1;
      float p0 = exp2fast(st0[r0]);
      float p1 = exp2fast(st0[r1]);
      float p2 = exp2fast(st1[r0]);
      float p3 = exp2fast(st1[r1]);
      lsum += (p0 + p1) + (p2 + p3);
      bf16x2 v0 = {(__bf16)p0, (__bf16)p1};
      bf16x2 v1 = {(__bf16)p2, (__bf16)p3};
      pd[0][m] = __builtin_bit_cast(unsigned, v0);
      pd[1][m] = __builtin_bit_cast(unsigned, v1);
    }
    lrun += lsum;

    // ---- PV B-fragments: l <-> l+32 dword exchange ----
#pragma unroll
    for (int ot = 0; ot < 2; ot++)
#pragma unroll
      for (int hc = 0; hc < 2; hc++) {
        pl32swap(pd[ot][4 * hc + 0], pd[ot][4 * hc + 2]);
        pl32swap(pd[ot][4 * hc + 1], pd[ot][4 * hc + 3]);
      }

    // ---- O^T += V^T * P^T ----
    __builtin_amdgcn_s_setprio(1);
#pragma unroll
    for (int cc = 0; cc < 4; cc++) {
      u32x4 pu = {pd[cc >> 1][4 * (cc & 1) + 0], pd[cc >> 1][4 * (cc & 1) + 1],
                  pd[cc >> 1][4 * (cc & 1) + 2], pd[cc >> 1][4 * (cc & 1) + 3]};
      bf16x8 pf = __builtin_bit_cast(bf16x8, pu);
      int u = ((cc * 2 + h5) ^ sA) * 8;
      bf16x8 vf0 = *(const bf16x8*)&Vb[l31 * 64 + u];
      bf16x8 vf1 = *(const bf16x8*)&Vb[(32 + l31) * 64 + u];
      accO0 = __builtin_amdgcn_mfma_f32_32x32x16_bf16(vf0, pf, accO0, 0, 0, 0);
      accO1 = __builtin_amdgcn_mfma_f32_32x32x16_bf16(vf1, pf, accO1, 0, 0, 0);
    }
    __builtin_amdgcn_s_setprio(0);

    asm volatile("s_waitcnt vmcnt(0)" ::: "memory");
    __syncthreads();
    cur ^= 1;
    mw = mwn;
  }

  // ---- write f32 partials (unnormalized) ----
  float* op = opart + ((((long long)z * 32 + bh) * 2048 + qglob) * 64);
#pragma unroll
  for (int m = 0; m < 4; m++) {
    int d0 = 8 * m + 4 * h5;
    f32x4 o0 = {accO0[4 * m + 0], accO0[4 * m + 1], accO0[4 * m + 2], accO0[4 * m + 3]};
    f32x4 o1 = {accO1[4 * m + 0], accO1[4 * m + 1], accO1[4 * m + 2], accO1[4 * m + 3]};
    *(f32x4*)&op[d0] = o0;
    *(f32x4*)&op[32 + d0] = o1;
  }
  float ltot = lrun + __shfl_xor(lrun, 32);
  if (h5 == 0) lpart[(long long)z * 65536 + bh * 2048 + qglob] = ltot;
}

// combine: y = (O0 + O1) / (l0 + l1), bf16 [B,T,C]
__global__ __launch_bounds__(256) void combine(const float* __restrict__ p0,
                                               const float* __restrict__ p1,
                                               const float* __restrict__ l0,
                                               const float* __restrict__ l1,
                                               unsigned short* __restrict__ yb) {
  int idx = blockIdx.x * 256 + threadIdx.x;   // [bh][q][d4]
  int bhq = idx >> 4, d4 = idx & 15;
  float4 a = ((const float4*)p0)[idx];
  float4 c = ((const float4*)p1)[idx];
  float linv = 1.0f / (l0[bhq] + l1[bhq]);
  int bh = bhq >> 11, q = bhq & 2047;
  int b = bh >> 3, h = bh & 7;
  unsigned short* dst = yb + ((long long)(b * 2048 + q)) * 512 + h * 64 + d4 * 4;
  bf16x4 o = {(__bf16)((a.x + c.x) * linv), (__bf16)((a.y + c.y) * linv),
              (__bf16)((a.z + c.z) * linv), (__bf16)((a.w + c.w) * linv)};
  *(bf16x4*)dst = o;
}

// ---------------- launcher ----------------

extern "C" void kernel_launch(void* const* d_in, const int* in_sizes, int n_in,
                              void* d_out, int out_size, void* d_ws, size_t ws_size,
                              hipStream_t stream) {
  const float* x      = (const float*)d_in[0];
  const int*   adj    = (const int*)d_in[1];
  const float* w_qkv  = (const float*)d_in[2];
  const float* b_qkv  = (const float*)d_in[3];
  const float* w_proj = (const float*)d_in[4];
  const float* b_proj = (const float*)d_in[5];
  float* out = (float*)d_out;

  char* ws = (char*)d_ws;
  unsigned short* xb  = (unsigned short*)(ws);              // 8.4MB  (reused as yb)
  unsigned short* qb  = (unsigned short*)(ws + 8388608);    // 8.4MB
  unsigned short* kbf = (unsigned short*)(ws + 16777216);   // 8.4MB
  unsigned short* vtb = (unsigned short*)(ws + 25165824);   // 8.4MB
  unsigned short* wqt = (unsigned short*)(ws + 33554432);   // 1.57MB
  unsigned short* wpt = (unsigned short*)(ws + 35127296);   // 0.52MB
  unsigned long long* mb = (unsigned long long*)(ws + 35651584); // 2MB
  float* opart = (float*)(ws + 37748736);                   // 32MB (2 x 16MB: z=0 at +0, z=1 at +16MB)
  float* lpart = (float*)(ws + 71303168);                   // 0.5MB (end ~68.5MB)
  unsigned short* yb = xb;  // x is dead after gemm_qkv

  prep<<<dim3(21504), dim3(256), 0, stream>>>(x, xb, w_qkv, wqt, w_proj, wpt, adj, mb);
  gemm_qkv<<<dim3(64, 12), dim3(256), 0, stream>>>(xb, wqt, b_qkv, qb, kbf, vtb);
  attn<<<dim3(2048), dim3(128), 0, stream>>>(qb, kbf, vtb, mb, opart, lpart);
  // z=1 O-partial lives at opart + 32*2048*64 floats = +16777216 bytes (was the round-4 bug)
  combine<<<dim3(4096), dim3(256), 0, stream>>>(opart, opart + 16777216 / 4,
                                                lpart, lpart + 65536, yb);
  gemm_proj<<<dim3(64, 4), dim3(256), 0, stream>>>(yb, wpt, b_proj, out);
}

// Round 6
// 118.948 us; speedup vs baseline: 1.2040x; 1.2040x over previous
//
#include <hip/hip_runtime.h>
#include <stdint.h>

// Problem constants: B=4, T=2048, C=512, H=8, D=64
typedef __attribute__((ext_vector_type(8))) __bf16 bf16x8;
typedef __attribute__((ext_vector_type(4))) __bf16 bf16x4;
typedef __attribute__((ext_vector_type(2))) __bf16 bf16x2;
typedef __attribute__((ext_vector_type(4))) float f32x4;
typedef __attribute__((ext_vector_type(16))) float f32x16;
typedef __attribute__((ext_vector_type(4))) unsigned u32x4;
typedef __attribute__((ext_vector_type(2))) int i32x2;

__device__ __forceinline__ unsigned short f2bf(float f) {
  unsigned u = __float_as_uint(f);
  u += 0x7FFFu + ((u >> 16) & 1u);   // round-to-nearest-even
  return (unsigned short)(u >> 16);
}

__device__ __forceinline__ float exp2fast(float x) {
#if __has_builtin(__builtin_amdgcn_exp2f)
  return __builtin_amdgcn_exp2f(x);
#else
  return __expf(x * 0.6931471805599453f);
#endif
}

__device__ __forceinline__ void pl32swap(unsigned &a, unsigned &b) {
#if __has_builtin(__builtin_amdgcn_permlane32_swap)
  i32x2 r = __builtin_amdgcn_permlane32_swap((int)a, (int)b, false, false);
  a = (unsigned)r[0]; b = (unsigned)r[1];
#else
  asm volatile("v_permlane32_swap_b32 %0, %1" : "+v"(a), "+v"(b));
#endif
}

// rows r, r+8, r+16, r+24 get distinct octets (2-way max aliasing anywhere)
__device__ __forceinline__ int swz8(int r) { return (r & 7) ^ ((r >> 3) & 3); }

__device__ __forceinline__ void gload16(const unsigned short* src, unsigned short* ldsdst) {
  __builtin_amdgcn_global_load_lds(
      (const __attribute__((address_space(1))) unsigned int*)src,
      (__attribute__((address_space(3))) unsigned int*)ldsdst, 16, 0, 0);
}

// Stage 8 rows x 64 bf16 (128B/row) into LDS tile (linear dest), with the
// global-source octet XOR-swizzled by swz8(row) so swizzled reads are
// bank-conflict-free (G21: swizzle source+read, dest stays linear).
__device__ __forceinline__ void stage8(const unsigned short* gbase, long long strideElems,
                                       unsigned short* ldsTile, int rowBase) {
  const int lane = threadIdx.x & 63;
  const int r = rowBase + (lane >> 3);
  const int oct = (lane & 7) ^ swz8(r);
  gload16(gbase + (long long)r * strideElems + oct * 8, ldsTile + rowBase * 64);
}

// ---------------- merged prep kernel ----------------

__global__ __launch_bounds__(256) void prep(const float* __restrict__ x,
                                            unsigned short* __restrict__ xb,
                                            const float* __restrict__ wq,
                                            unsigned short* __restrict__ wqt,
                                            const float* __restrict__ wp,
                                            unsigned short* __restrict__ wpt,
                                            const int* __restrict__ adj,
                                            unsigned long long* __restrict__ mb) {
  int blk = blockIdx.x;
  if (blk < 16384) {
    int tid = blk * 256 + threadIdx.x;
    int4 v = ((const int4*)adj)[tid];
    unsigned n = (v.x != 0 ? 1u : 0u) | (v.y != 0 ? 2u : 0u) |
                 (v.z != 0 ? 4u : 0u) | (v.w != 0 ? 8u : 0u);
    unsigned long long part = (unsigned long long)n << ((threadIdx.x & 15) * 4);
    part |= __shfl_xor(part, 1);
    part |= __shfl_xor(part, 2);
    part |= __shfl_xor(part, 4);
    part |= __shfl_xor(part, 8);
    if ((threadIdx.x & 15) == 0) mb[tid >> 4] = part;
    return;
  }
  blk -= 16384;
  if (blk < 4096) {
    int i = (blk * 256 + threadIdx.x) * 4;
    float4 v = *(const float4*)(x + i);
    ushort4 o;
    o.x = f2bf(v.x); o.y = f2bf(v.y); o.z = f2bf(v.z); o.w = f2bf(v.w);
    *(ushort4*)(xb + i) = o;
    return;
  }
  blk -= 4096;
  const float* w; unsigned short* wt; int N; int bx, by;
  if (blk < 768) { w = wq; wt = wqt; N = 1536; bx = blk & 15; by = blk >> 4; }
  else { blk -= 768; w = wp; wt = wpt; N = 512; bx = blk & 15; by = blk >> 4; }
  __shared__ float tile[32][33];
  int k0 = bx * 32, n0 = by * 32;
  int tx = threadIdx.x & 31, ty = threadIdx.x >> 5;
#pragma unroll
  for (int i = 0; i < 4; i++)
    tile[ty + i * 8][tx] = w[(long long)(k0 + ty + i * 8) * N + n0 + tx];
  __syncthreads();
#pragma unroll
  for (int i = 0; i < 4; i++)
    wt[(long long)(n0 + ty + i * 8) * 512 + k0 + tx] = f2bf(tile[tx][ty + i * 8]);
}

// ---------------- GEMM core: C[128x128] = A[M,512] * Wt[N,512]^T ----------------

__device__ __forceinline__ void gemm_core(const unsigned short* __restrict__ A,
                                          const unsigned short* __restrict__ Wt,
                                          unsigned short (*Al)[128 * 64],
                                          unsigned short (*Bl)[128 * 64],
                                          int m0, int n0, f32x4 acc[4][4]) {
  const int lane = threadIdx.x & 63;
  const int wid = threadIdx.x >> 6;
  const int c = lane & 15, g = lane >> 4;
  const int wm = wid >> 1, wn = wid & 1;
  const unsigned short* Ab = A + (long long)m0 * 512;
  const unsigned short* Bb = Wt + (long long)n0 * 512;

#pragma unroll
  for (int i = 0; i < 4; i++) stage8(Ab, 512, Al[0], wid * 32 + i * 8);
#pragma unroll
  for (int i = 0; i < 4; i++) stage8(Bb, 512, Bl[0], wid * 32 + i * 8);
  asm volatile("s_waitcnt vmcnt(0)" ::: "memory");
  __syncthreads();

  int cur = 0;
  for (int k0 = 0; k0 < 512; k0 += 64) {
    if (k0 + 64 < 512) {
#pragma unroll
      for (int i = 0; i < 4; i++) stage8(Ab + k0 + 64, 512, Al[cur ^ 1], wid * 32 + i * 8);
#pragma unroll
      for (int i = 0; i < 4; i++) stage8(Bb + k0 + 64, 512, Bl[cur ^ 1], wid * 32 + i * 8);
    }
#pragma unroll
    for (int kk = 0; kk < 2; kk++) {
      bf16x8 af[4], bfr[4];
#pragma unroll
      for (int mi = 0; mi < 4; mi++) {
        int row = wm * 64 + mi * 16 + c;
        af[mi] = *(const bf16x8*)&Al[cur][row * 64 + (((kk << 2) | g) ^ swz8(row)) * 8];
      }
#pragma unroll
      for (int ni = 0; ni < 4; ni++) {
        int row = wn * 64 + ni * 16 + c;
        bfr[ni] = *(const bf16x8*)&Bl[cur][row * 64 + (((kk << 2) | g) ^ swz8(row)) * 8];
      }
#pragma unroll
      for (int mi = 0; mi < 4; mi++)
#pragma unroll
        for (int ni = 0; ni < 4; ni++)
          acc[mi][ni] = __builtin_amdgcn_mfma_f32_16x16x32_bf16(af[mi], bfr[ni], acc[mi][ni], 0, 0, 0);
    }
    asm volatile("s_waitcnt vmcnt(0)" ::: "memory");
    __syncthreads();
    cur ^= 1;
  }
}

__global__ __launch_bounds__(256) void gemm_qkv(const unsigned short* __restrict__ xb,
                                                const unsigned short* __restrict__ wqt,
                                                const float* __restrict__ bqkv,
                                                unsigned short* __restrict__ qb,
                                                unsigned short* __restrict__ kb,
                                                unsigned short* __restrict__ vtb) {
  __shared__ __align__(16) unsigned short Al[2][128 * 64];
  __shared__ __align__(16) unsigned short Bl[2][128 * 64];
  f32x4 acc[4][4] = {};
  int m0 = blockIdx.x * 128, n0 = blockIdx.y * 128;
  gemm_core(xb, wqt, Al, Bl, m0, n0, acc);
  const int lane = threadIdx.x & 63;
  const int wid = threadIdx.x >> 6;
  const int c = lane & 15, g = lane >> 4;
  const int wm = wid >> 1, wn = wid & 1;
#pragma unroll
  for (int ni = 0; ni < 4; ni++) {
    int n = n0 + wn * 64 + ni * 16 + c;
    float bv = bqkv[n];
    int which = n >> 9;
    int h = (n & 511) >> 6, d = n & 63;
#pragma unroll
    for (int mi = 0; mi < 4; mi++) {
      int mbase = m0 + wm * 64 + mi * 16 + g * 4;
#pragma unroll
      for (int j = 0; j < 4; j++) {
        int m = mbase + j;
        int b = m >> 11, t = m & 2047;
        int bh = b * 8 + h;
        float v = acc[mi][ni][j] + bv;
        if (which == 0)      qb[(bh * 2048 + t) * 64 + d] = f2bf(v * 0.18033688011112042f);
        else if (which == 1) kb[(bh * 2048 + t) * 64 + d] = f2bf(v);
        else                 vtb[(bh * 64 + d) * 2048 + t] = f2bf(v);
      }
    }
  }
}

__global__ __launch_bounds__(256) void gemm_proj(const unsigned short* __restrict__ yb,
                                                 const unsigned short* __restrict__ wpt,
                                                 const float* __restrict__ bproj,
                                                 float* __restrict__ out) {
  __shared__ __align__(16) unsigned short Al[2][128 * 64];
  __shared__ __align__(16) unsigned short Bl[2][128 * 64];
  f32x4 acc[4][4] = {};
  int m0 = blockIdx.x * 128, n0 = blockIdx.y * 128;
  gemm_core(yb, wpt, Al, Bl, m0, n0, acc);
  const int lane = threadIdx.x & 63;
  const int wid = threadIdx.x >> 6;
  const int c = lane & 15, g = lane >> 4;
  const int wm = wid >> 1, wn = wid & 1;
#pragma unroll
  for (int ni = 0; ni < 4; ni++) {
    int n = n0 + wn * 64 + ni * 16 + c;
    float bv = bproj[n];
#pragma unroll
    for (int mi = 0; mi < 4; mi++) {
      int mbase = m0 + wm * 64 + mi * 16 + g * 4;
#pragma unroll
      for (int j = 0; j < 4; j++)
        out[(long long)(mbase + j) * 512 + n] = acc[mi][ni][j] + bv;
    }
  }
}

// ---------------- flash attention, 32x32 MFMA, 4-wave shared staging ----------------
// Grid: 512 1D blocks -> (bh = bid&31 [XCD-colocated], qblock of 128 rows).
// 4 waves x 32 q-rows share one double-buffered K/V LDS tile (KV=64): LDS cost
// per wave halves vs 2-wave -> ~2x waves/CU; staging is 4 stage8/wave/tile.
// S^T = K*Q^T (lane owns 32 scores of its q-row); mask enters as the MFMA
// C-operand seed (0/-1e30) read from a 16-entry nibble LUT in LDS (8
// broadcast ds_read_b128 replace ~96 VALU bit-test ops — round-3 regression
// undone). No-max exp2 softmax; P stays in registers via permlane32_swap;
// O^T = V^T * P^T from pre-transposed V.
__global__ __launch_bounds__(256) void attn(const unsigned short* __restrict__ qb,
                                            const unsigned short* __restrict__ kb,
                                            const unsigned short* __restrict__ vtb,
                                            const unsigned long long* __restrict__ mbits,
                                            unsigned short* __restrict__ yb) {
  __shared__ __align__(16) unsigned short Kl[2][64 * 64];
  __shared__ __align__(16) unsigned short Vl[2][64 * 64];
  __shared__ __align__(16) float lut4[16][4];   // nibble -> f32x4 seed (0 / -1e30)
  const int lane = threadIdx.x & 63;
  const int w = threadIdx.x >> 6;          // wave 0..3
  const int l31 = lane & 31, h5 = lane >> 5;
  const int sA = swz8(l31);                // swz8(l31+32) == swz8(l31)
  const int bid = blockIdx.x;
  const int bh = bid & 31;                 // xcd = bid%8 = bh%8 -> K/V L2-resident
  const int q0 = (bid >> 5) * 128;
  const int b = bh >> 3, h = bh & 7;
  const int qglob = q0 + w * 32 + l31;

  if (threadIdx.x < 16) {
    int n = threadIdx.x;
#pragma unroll
    for (int j = 0; j < 4; j++) lut4[n][j] = ((n >> j) & 1) ? 0.0f : -1e30f;
  }

  const unsigned short* qptr = qb + ((long long)bh * 2048 + qglob) * 64;
  bf16x8 qf[4];
#pragma unroll
  for (int cc = 0; cc < 4; cc++) qf[cc] = *(const bf16x8*)(qptr + cc * 16 + h5 * 8);

  const unsigned long long* mrow = mbits + ((long long)b * 2048 + qglob) * 32;
  const unsigned short* kbase = kb + (long long)bh * 2048 * 64;
  const unsigned short* vbase = vtb + (long long)bh * 64 * 2048;

  f32x16 accO0 = {0,0,0,0, 0,0,0,0, 0,0,0,0, 0,0,0,0};
  f32x16 accO1 = {0,0,0,0, 0,0,0,0, 0,0,0,0, 0,0,0,0};
  float lrun = 0.0f;

  // prologue: 4 waves cooperatively stage tile 0 (wave w: rows w*16..w*16+15)
  stage8(kbase, 64, Kl[0], w * 16);
  stage8(kbase, 64, Kl[0], w * 16 + 8);
  stage8(vbase, 2048, Vl[0], w * 16);
  stage8(vbase, 2048, Vl[0], w * 16 + 8);
  unsigned long long mw = mrow[0];
  asm volatile("s_waitcnt vmcnt(0)" ::: "memory");
  __syncthreads();

  int cur = 0;
  for (int t = 0; t < 32; ++t) {
    unsigned long long mwn = 0;
    if (t < 31) {
      int kv0 = (t + 1) * 64;
      stage8(kbase + (long long)kv0 * 64, 64, Kl[cur ^ 1], w * 16);
      stage8(kbase + (long long)kv0 * 64, 64, Kl[cur ^ 1], w * 16 + 8);
      stage8(vbase + kv0, 2048, Vl[cur ^ 1], w * 16);
      stage8(vbase + kv0, 2048, Vl[cur ^ 1], w * 16 + 8);
      mwn = mrow[t + 1];
    }

    // ---- seed S^T accumulators from the nibble LUT ----
    // C reg r of tile ot: kv = ot*32 + (r&3) + 8*(r>>2) + 4*h5
    // quad j of st0 (r=4j..4j+3) <-> nibble (2j + h5) of low32; st1 <-> high32
    unsigned lo = (unsigned)mw, hi = (unsigned)(mw >> 32);
    f32x16 st0, st1;
#pragma unroll
    for (int j = 0; j < 4; j++) {
      f32x4 s0 = *(const f32x4*)lut4[(lo >> (8 * j + 4 * h5)) & 0xF];
      f32x4 s1 = *(const f32x4*)lut4[(hi >> (8 * j + 4 * h5)) & 0xF];
#pragma unroll
      for (int i = 0; i < 4; i++) { st0[4 * j + i] = s0[i]; st1[4 * j + i] = s1[i]; }
    }

    // ---- S^T = K * Q^T ----
    const unsigned short* Kb = &Kl[cur][0];
    const unsigned short* Vb = &Vl[cur][0];
    __builtin_amdgcn_s_setprio(1);
#pragma unroll
    for (int cc = 0; cc < 4; cc++) {
      int u = ((cc * 2 + h5) ^ sA) * 8;
      bf16x8 kf0 = *(const bf16x8*)&Kb[l31 * 64 + u];
      bf16x8 kf1 = *(const bf16x8*)&Kb[(32 + l31) * 64 + u];
      st0 = __builtin_amdgcn_mfma_f32_32x32x16_bf16(kf0, qf[cc], st0, 0, 0, 0);
      st1 = __builtin_amdgcn_mfma_f32_32x32x16_bf16(kf1, qf[cc], st1, 0, 0, 0);
    }
    __builtin_amdgcn_s_setprio(0);

    // ---- exp2 softmax (masked entries hit exp2(-1e30) = 0), pack bf16 ----
    unsigned pd[2][8];
    float lsum = 0.0f;
#pragma unroll
    for (int m = 0; m < 8; m++) {
      const int r0 = 2 * m, r1 = 2 * m + 1;
      float p0 = exp2fast(st0[r0]);
      float p1 = exp2fast(st0[r1]);
      float p2 = exp2fast(st1[r0]);
      float p3 = exp2fast(st1[r1]);
      lsum += (p0 + p1) + (p2 + p3);
      bf16x2 v0 = {(__bf16)p0, (__bf16)p1};
      bf16x2 v1 = {(__bf16)p2, (__bf16)p3};
      pd[0][m] = __builtin_bit_cast(unsigned, v0);
      pd[1][m] = __builtin_bit_cast(unsigned, v1);
    }
    lrun += lsum;

    // ---- PV B-fragments: l <-> l+32 dword exchange ----
#pragma unroll
    for (int ot = 0; ot < 2; ot++)
#pragma unroll
      for (int hc = 0; hc < 2; hc++) {
        pl32swap(pd[ot][4 * hc + 0], pd[ot][4 * hc + 2]);
        pl32swap(pd[ot][4 * hc + 1], pd[ot][4 * hc + 3]);
      }

    // ---- O^T += V^T * P^T ----
    __builtin_amdgcn_s_setprio(1);
#pragma unroll
    for (int cc = 0; cc < 4; cc++) {
      u32x4 pu = {pd[cc >> 1][4 * (cc & 1) + 0], pd[cc >> 1][4 * (cc & 1) + 1],
                  pd[cc >> 1][4 * (cc & 1) + 2], pd[cc >> 1][4 * (cc & 1) + 3]};
      bf16x8 pf = __builtin_bit_cast(bf16x8, pu);
      int u = ((cc * 2 + h5) ^ sA) * 8;
      bf16x8 vf0 = *(const bf16x8*)&Vb[l31 * 64 + u];
      bf16x8 vf1 = *(const bf16x8*)&Vb[(32 + l31) * 64 + u];
      accO0 = __builtin_amdgcn_mfma_f32_32x32x16_bf16(vf0, pf, accO0, 0, 0, 0);
      accO1 = __builtin_amdgcn_mfma_f32_32x32x16_bf16(vf1, pf, accO1, 0, 0, 0);
    }
    __builtin_amdgcn_s_setprio(0);

    asm volatile("s_waitcnt vmcnt(0)" ::: "memory");
    __syncthreads();
    cur ^= 1;
    mw = mwn;
  }

  float linv = 1.0f / (lrun + __shfl_xor(lrun, 32));
  unsigned short* yrow = yb + ((long long)(b * 2048 + qglob)) * 512 + h * 64;
#pragma unroll
  for (int m = 0; m < 4; m++) {
    int d0 = 8 * m + 4 * h5;
    bf16x4 o0 = {(__bf16)(accO0[4 * m + 0] * linv), (__bf16)(accO0[4 * m + 1] * linv),
                 (__bf16)(accO0[4 * m + 2] * linv), (__bf16)(accO0[4 * m + 3] * linv)};
    bf16x4 o1 = {(__bf16)(accO1[4 * m + 0] * linv), (__bf16)(accO1[4 * m + 1] * linv),
                 (__bf16)(accO1[4 * m + 2] * linv), (__bf16)(accO1[4 * m + 3] * linv)};
    *(bf16x4*)&yrow[d0] = o0;
    *(bf16x4*)&yrow[32 + d0] = o1;
  }
}

// ---------------- launcher ----------------

extern "C" void kernel_launch(void* const* d_in, const int* in_sizes, int n_in,
                              void* d_out, int out_size, void* d_ws, size_t ws_size,
                              hipStream_t stream) {
  const float* x      = (const float*)d_in[0];
  const int*   adj    = (const int*)d_in[1];
  const float* w_qkv  = (const float*)d_in[2];
  const float* b_qkv  = (const float*)d_in[3];
  const float* w_proj = (const float*)d_in[4];
  const float* b_proj = (const float*)d_in[5];
  float* out = (float*)d_out;

  char* ws = (char*)d_ws;
  unsigned short* xb  = (unsigned short*)(ws);              // 8.4MB  (reused as yb)
  unsigned short* qb  = (unsigned short*)(ws + 8388608);    // 8.4MB
  unsigned short* kbf = (unsigned short*)(ws + 16777216);   // 8.4MB
  unsigned short* vtb = (unsigned short*)(ws + 25165824);   // 8.4MB
  unsigned short* wqt = (unsigned short*)(ws + 33554432);   // 1.57MB
  unsigned short* wpt = (unsigned short*)(ws + 35127296);   // 0.52MB
  unsigned long long* mb = (unsigned long long*)(ws + 35651584); // 2MB  (end 37.75MB)
  unsigned short* yb = xb;  // x is dead after gemm_qkv

  prep<<<dim3(21504), dim3(256), 0, stream>>>(x, xb, w_qkv, wqt, w_proj, wpt, adj, mb);
  gemm_qkv<<<dim3(64, 12), dim3(256), 0, stream>>>(xb, wqt, b_qkv, qb, kbf, vtb);
  attn<<<dim3(512), dim3(256), 0, stream>>>(qb, kbf, vtb, mb, yb);
  gemm_proj<<<dim3(64, 4), dim3(256), 0, stream>>>(yb, wpt, b_proj, out);
}

// Round 7
// 117.123 us; speedup vs baseline: 1.2228x; 1.0156x over previous
//
#include <hip/hip_runtime.h>
#include <stdint.h>

// Problem constants: B=4, T=2048, C=512, H=8, D=64
typedef __attribute__((ext_vector_type(8))) __bf16 bf16x8;
typedef __attribute__((ext_vector_type(4))) __bf16 bf16x4;
typedef __attribute__((ext_vector_type(2))) __bf16 bf16x2;
typedef __attribute__((ext_vector_type(4))) float f32x4;
typedef __attribute__((ext_vector_type(16))) float f32x16;
typedef __attribute__((ext_vector_type(4))) unsigned u32x4;
typedef __attribute__((ext_vector_type(2))) int i32x2;

__device__ __forceinline__ unsigned short f2bf(float f) {
  unsigned u = __float_as_uint(f);
  u += 0x7FFFu + ((u >> 16) & 1u);   // round-to-nearest-even
  return (unsigned short)(u >> 16);
}

__device__ __forceinline__ float exp2fast(float x) {
#if __has_builtin(__builtin_amdgcn_exp2f)
  return __builtin_amdgcn_exp2f(x);
#else
  return __expf(x * 0.6931471805599453f);
#endif
}

__device__ __forceinline__ void pl32swap(unsigned &a, unsigned &b) {
#if __has_builtin(__builtin_amdgcn_permlane32_swap)
  i32x2 r = __builtin_amdgcn_permlane32_swap((int)a, (int)b, false, false);
  a = (unsigned)r[0]; b = (unsigned)r[1];
#else
  asm volatile("v_permlane32_swap_b32 %0, %1" : "+v"(a), "+v"(b));
#endif
}

// rows r, r+8, r+16, r+24 get distinct octets (2-way max aliasing anywhere)
__device__ __forceinline__ int swz8(int r) { return (r & 7) ^ ((r >> 3) & 3); }

__device__ __forceinline__ void gload16(const unsigned short* src, unsigned short* ldsdst) {
  __builtin_amdgcn_global_load_lds(
      (const __attribute__((address_space(1))) unsigned int*)src,
      (__attribute__((address_space(3))) unsigned int*)ldsdst, 16, 0, 0);
}

// Stage 8 rows x 64 bf16 (128B/row) into LDS tile (linear dest), with the
// global-source octet XOR-swizzled by swz8(row) so swizzled reads are
// bank-conflict-free (G21: swizzle source+read, dest stays linear).
__device__ __forceinline__ void stage8(const unsigned short* gbase, long long strideElems,
                                       unsigned short* ldsTile, int rowBase) {
  const int lane = threadIdx.x & 63;
  const int r = rowBase + (lane >> 3);
  const int oct = (lane & 7) ^ swz8(r);
  gload16(gbase + (long long)r * strideElems + oct * 8, ldsTile + rowBase * 64);
}

// ---------------- merged prep kernel ----------------

__global__ __launch_bounds__(256) void prep(const float* __restrict__ x,
                                            unsigned short* __restrict__ xb,
                                            const float* __restrict__ wq,
                                            unsigned short* __restrict__ wqt,
                                            const float* __restrict__ wp,
                                            unsigned short* __restrict__ wpt,
                                            const int* __restrict__ adj,
                                            unsigned long long* __restrict__ mb) {
  int blk = blockIdx.x;
  if (blk < 16384) {
    int tid = blk * 256 + threadIdx.x;
    int4 v = ((const int4*)adj)[tid];
    unsigned n = (v.x != 0 ? 1u : 0u) | (v.y != 0 ? 2u : 0u) |
                 (v.z != 0 ? 4u : 0u) | (v.w != 0 ? 8u : 0u);
    unsigned long long part = (unsigned long long)n << ((threadIdx.x & 15) * 4);
    part |= __shfl_xor(part, 1);
    part |= __shfl_xor(part, 2);
    part |= __shfl_xor(part, 4);
    part |= __shfl_xor(part, 8);
    if ((threadIdx.x & 15) == 0) mb[tid >> 4] = part;
    return;
  }
  blk -= 16384;
  if (blk < 4096) {
    int i = (blk * 256 + threadIdx.x) * 4;
    float4 v = *(const float4*)(x + i);
    ushort4 o;
    o.x = f2bf(v.x); o.y = f2bf(v.y); o.z = f2bf(v.z); o.w = f2bf(v.w);
    *(ushort4*)(xb + i) = o;
    return;
  }
  blk -= 4096;
  const float* w; unsigned short* wt; int N; int bx, by;
  if (blk < 768) { w = wq; wt = wqt; N = 1536; bx = blk & 15; by = blk >> 4; }
  else { blk -= 768; w = wp; wt = wpt; N = 512; bx = blk & 15; by = blk >> 4; }
  __shared__ float tile[32][33];
  int k0 = bx * 32, n0 = by * 32;
  int tx = threadIdx.x & 31, ty = threadIdx.x >> 5;
#pragma unroll
  for (int i = 0; i < 4; i++)
    tile[ty + i * 8][tx] = w[(long long)(k0 + ty + i * 8) * N + n0 + tx];
  __syncthreads();
#pragma unroll
  for (int i = 0; i < 4; i++)
    wt[(long long)(n0 + ty + i * 8) * 512 + k0 + tx] = f2bf(tile[tx][ty + i * 8]);
}

// ---------------- GEMM core: C[128x128] = A[M,512] * Wt[N,512]^T ----------------
// m97 structure: single-buffered 32KB LDS (5 blocks/CU), per K-step:
// barrier; stage; vmcnt(0); barrier; compute.

__device__ __forceinline__ void gemm_core(const unsigned short* __restrict__ A,
                                          const unsigned short* __restrict__ Wt,
                                          unsigned short* Al, unsigned short* Bl,
                                          int m0, int n0, f32x4 acc[4][4]) {
  const int lane = threadIdx.x & 63;
  const int wid = threadIdx.x >> 6;
  const int c = lane & 15, g = lane >> 4;
  const int wm = wid >> 1, wn = wid & 1;
  const unsigned short* Ab = A + (long long)m0 * 512;
  const unsigned short* Bb = Wt + (long long)n0 * 512;

  for (int k0 = 0; k0 < 512; k0 += 64) {
    __syncthreads();
#pragma unroll
    for (int i = 0; i < 4; i++) stage8(Ab + k0, 512, Al, wid * 32 + i * 8);
#pragma unroll
    for (int i = 0; i < 4; i++) stage8(Bb + k0, 512, Bl, wid * 32 + i * 8);
    asm volatile("s_waitcnt vmcnt(0)" ::: "memory");
    __syncthreads();
#pragma unroll
    for (int kk = 0; kk < 2; kk++) {
      bf16x8 af[4], bfr[4];
#pragma unroll
      for (int mi = 0; mi < 4; mi++) {
        int row = wm * 64 + mi * 16 + c;
        af[mi] = *(const bf16x8*)&Al[row * 64 + (((kk << 2) | g) ^ swz8(row)) * 8];
      }
#pragma unroll
      for (int ni = 0; ni < 4; ni++) {
        int row = wn * 64 + ni * 16 + c;
        bfr[ni] = *(const bf16x8*)&Bl[row * 64 + (((kk << 2) | g) ^ swz8(row)) * 8];
      }
#pragma unroll
      for (int mi = 0; mi < 4; mi++)
#pragma unroll
        for (int ni = 0; ni < 4; ni++)
          acc[mi][ni] = __builtin_amdgcn_mfma_f32_16x16x32_bf16(af[mi], bfr[ni], acc[mi][ni], 0, 0, 0);
    }
  }
}

__global__ __launch_bounds__(256) void gemm_qkv(const unsigned short* __restrict__ xb,
                                                const unsigned short* __restrict__ wqt,
                                                const float* __restrict__ bqkv,
                                                unsigned short* __restrict__ qb,
                                                unsigned short* __restrict__ kb,
                                                unsigned short* __restrict__ vtb) {
  __shared__ __align__(16) unsigned short Al[128 * 64];
  __shared__ __align__(16) unsigned short Bl[128 * 64];
  f32x4 acc[4][4] = {};
  int m0 = blockIdx.x * 128, n0 = blockIdx.y * 128;
  gemm_core(xb, wqt, Al, Bl, m0, n0, acc);
  const int lane = threadIdx.x & 63;
  const int wid = threadIdx.x >> 6;
  const int c = lane & 15, g = lane >> 4;
  const int wm = wid >> 1, wn = wid & 1;
#pragma unroll
  for (int ni = 0; ni < 4; ni++) {
    int n = n0 + wn * 64 + ni * 16 + c;
    float bv = bqkv[n];
    int which = n >> 9;
    int h = (n & 511) >> 6, d = n & 63;
#pragma unroll
    for (int mi = 0; mi < 4; mi++) {
      int mbase = m0 + wm * 64 + mi * 16 + g * 4;   // 4 consecutive t, same batch
      int b = mbase >> 11, t0 = mbase & 2047;
      int bh = b * 8 + h;
      if (which == 2) {
        // V transposed [bh][d][t]: 4 consecutive t -> one 8B store
        ushort4 o;
        o.x = f2bf(acc[mi][ni][0] + bv); o.y = f2bf(acc[mi][ni][1] + bv);
        o.z = f2bf(acc[mi][ni][2] + bv); o.w = f2bf(acc[mi][ni][3] + bv);
        *(ushort4*)&vtb[((long long)bh * 64 + d) * 2048 + t0] = o;
      } else if (which == 0) {
#pragma unroll
        for (int j = 0; j < 4; j++)
          qb[(bh * 2048 + t0 + j) * 64 + d] = f2bf((acc[mi][ni][j] + bv) * 0.18033688011112042f);
      } else {
#pragma unroll
        for (int j = 0; j < 4; j++)
          kb[(bh * 2048 + t0 + j) * 64 + d] = f2bf(acc[mi][ni][j] + bv);
      }
    }
  }
}

__global__ __launch_bounds__(256) void gemm_proj(const unsigned short* __restrict__ yb,
                                                 const unsigned short* __restrict__ wpt,
                                                 const float* __restrict__ bproj,
                                                 float* __restrict__ out) {
  __shared__ __align__(16) unsigned short Al[128 * 64];
  __shared__ __align__(16) unsigned short Bl[128 * 64];
  f32x4 acc[4][4] = {};
  int m0 = blockIdx.x * 128, n0 = blockIdx.y * 128;
  gemm_core(yb, wpt, Al, Bl, m0, n0, acc);
  const int lane = threadIdx.x & 63;
  const int wid = threadIdx.x >> 6;
  const int c = lane & 15, g = lane >> 4;
  const int wm = wid >> 1, wn = wid & 1;
#pragma unroll
  for (int ni = 0; ni < 4; ni++) {
    int n = n0 + wn * 64 + ni * 16 + c;
    float bv = bproj[n];
#pragma unroll
    for (int mi = 0; mi < 4; mi++) {
      int mbase = m0 + wm * 64 + mi * 16 + g * 4;
#pragma unroll
      for (int j = 0; j < 4; j++)
        out[(long long)(mbase + j) * 512 + n] = acc[mi][ni][j] + bv;
    }
  }
}

// ---------------- flash attention, 32x32 MFMA, 4-wave shared staging ----------------
// (unchanged from round 6 — this round isolates the GEMM buffering change)
__global__ __launch_bounds__(256) void attn(const unsigned short* __restrict__ qb,
                                            const unsigned short* __restrict__ kb,
                                            const unsigned short* __restrict__ vtb,
                                            const unsigned long long* __restrict__ mbits,
                                            unsigned short* __restrict__ yb) {
  __shared__ __align__(16) unsigned short Kl[2][64 * 64];
  __shared__ __align__(16) unsigned short Vl[2][64 * 64];
  __shared__ __align__(16) float lut4[16][4];   // nibble -> f32x4 seed (0 / -1e30)
  const int lane = threadIdx.x & 63;
  const int w = threadIdx.x >> 6;          // wave 0..3
  const int l31 = lane & 31, h5 = lane >> 5;
  const int sA = swz8(l31);                // swz8(l31+32) == swz8(l31)
  const int bid = blockIdx.x;
  const int bh = bid & 31;                 // xcd = bid%8 = bh%8 -> K/V L2-resident
  const int q0 = (bid >> 5) * 128;
  const int b = bh >> 3, h = bh & 7;
  const int qglob = q0 + w * 32 + l31;

  if (threadIdx.x < 16) {
    int n = threadIdx.x;
#pragma unroll
    for (int j = 0; j < 4; j++) lut4[n][j] = ((n >> j) & 1) ? 0.0f : -1e30f;
  }

  const unsigned short* qptr = qb + ((long long)bh * 2048 + qglob) * 64;
  bf16x8 qf[4];
#pragma unroll
  for (int cc = 0; cc < 4; cc++) qf[cc] = *(const bf16x8*)(qptr + cc * 16 + h5 * 8);

  const unsigned long long* mrow = mbits + ((long long)b * 2048 + qglob) * 32;
  const unsigned short* kbase = kb + (long long)bh * 2048 * 64;
  const unsigned short* vbase = vtb + (long long)bh * 64 * 2048;

  f32x16 accO0 = {0,0,0,0, 0,0,0,0, 0,0,0,0, 0,0,0,0};
  f32x16 accO1 = {0,0,0,0, 0,0,0,0, 0,0,0,0, 0,0,0,0};
  float lrun = 0.0f;

  // prologue: 4 waves cooperatively stage tile 0 (wave w: rows w*16..w*16+15)
  stage8(kbase, 64, Kl[0], w * 16);
  stage8(kbase, 64, Kl[0], w * 16 + 8);
  stage8(vbase, 2048, Vl[0], w * 16);
  stage8(vbase, 2048, Vl[0], w * 16 + 8);
  unsigned long long mw = mrow[0];
  asm volatile("s_waitcnt vmcnt(0)" ::: "memory");
  __syncthreads();

  int cur = 0;
  for (int t = 0; t < 32; ++t) {
    unsigned long long mwn = 0;
    if (t < 31) {
      int kv0 = (t + 1) * 64;
      stage8(kbase + (long long)kv0 * 64, 64, Kl[cur ^ 1], w * 16);
      stage8(kbase + (long long)kv0 * 64, 64, Kl[cur ^ 1], w * 16 + 8);
      stage8(vbase + kv0, 2048, Vl[cur ^ 1], w * 16);
      stage8(vbase + kv0, 2048, Vl[cur ^ 1], w * 16 + 8);
      mwn = mrow[t + 1];
    }

    // ---- seed S^T accumulators from the nibble LUT ----
    // C reg r of tile ot: kv = ot*32 + (r&3) + 8*(r>>2) + 4*h5
    unsigned lo = (unsigned)mw, hi = (unsigned)(mw >> 32);
    f32x16 st0, st1;
#pragma unroll
    for (int j = 0; j < 4; j++) {
      f32x4 s0 = *(const f32x4*)lut4[(lo >> (8 * j + 4 * h5)) & 0xF];
      f32x4 s1 = *(const f32x4*)lut4[(hi >> (8 * j + 4 * h5)) & 0xF];
#pragma unroll
      for (int i = 0; i < 4; i++) { st0[4 * j + i] = s0[i]; st1[4 * j + i] = s1[i]; }
    }

    // ---- S^T = K * Q^T ----
    const unsigned short* Kb = &Kl[cur][0];
    const unsigned short* Vb = &Vl[cur][0];
    __builtin_amdgcn_s_setprio(1);
#pragma unroll
    for (int cc = 0; cc < 4; cc++) {
      int u = ((cc * 2 + h5) ^ sA) * 8;
      bf16x8 kf0 = *(const bf16x8*)&Kb[l31 * 64 + u];
      bf16x8 kf1 = *(const bf16x8*)&Kb[(32 + l31) * 64 + u];
      st0 = __builtin_amdgcn_mfma_f32_32x32x16_bf16(kf0, qf[cc], st0, 0, 0, 0);
      st1 = __builtin_amdgcn_mfma_f32_32x32x16_bf16(kf1, qf[cc], st1, 0, 0, 0);
    }
    __builtin_amdgcn_s_setprio(0);

    // ---- exp2 softmax (masked entries hit exp2(-1e30) = 0), pack bf16 ----
    unsigned pd[2][8];
    float lsum = 0.0f;
#pragma unroll
    for (int m = 0; m < 8; m++) {
      const int r0 = 2 * m, r1 = 2 * m + 1;
      float p0 = exp2fast(st0[r0]);
      float p1 = exp2fast(st0[r1]);
      float p2 = exp2fast(st1[r0]);
      float p3 = exp2fast(st1[r1]);
      lsum += (p0 + p1) + (p2 + p3);
      bf16x2 v0 = {(__bf16)p0, (__bf16)p1};
      bf16x2 v1 = {(__bf16)p2, (__bf16)p3};
      pd[0][m] = __builtin_bit_cast(unsigned, v0);
      pd[1][m] = __builtin_bit_cast(unsigned, v1);
    }
    lrun += lsum;

    // ---- PV B-fragments: l <-> l+32 dword exchange ----
#pragma unroll
    for (int ot = 0; ot < 2; ot++)
#pragma unroll
      for (int hc = 0; hc < 2; hc++) {
        pl32swap(pd[ot][4 * hc + 0], pd[ot][4 * hc + 2]);
        pl32swap(pd[ot][4 * hc + 1], pd[ot][4 * hc + 3]);
      }

    // ---- O^T += V^T * P^T ----
    __builtin_amdgcn_s_setprio(1);
#pragma unroll
    for (int cc = 0; cc < 4; cc++) {
      u32x4 pu = {pd[cc >> 1][4 * (cc & 1) + 0], pd[cc >> 1][4 * (cc & 1) + 1],
                  pd[cc >> 1][4 * (cc & 1) + 2], pd[cc >> 1][4 * (cc & 1) + 3]};
      bf16x8 pf = __builtin_bit_cast(bf16x8, pu);
      int u = ((cc * 2 + h5) ^ sA) * 8;
      bf16x8 vf0 = *(const bf16x8*)&Vb[l31 * 64 + u];
      bf16x8 vf1 = *(const bf16x8*)&Vb[(32 + l31) * 64 + u];
      accO0 = __builtin_amdgcn_mfma_f32_32x32x16_bf16(vf0, pf, accO0, 0, 0, 0);
      accO1 = __builtin_amdgcn_mfma_f32_32x32x16_bf16(vf1, pf, accO1, 0, 0, 0);
    }
    __builtin_amdgcn_s_setprio(0);

    asm volatile("s_waitcnt vmcnt(0)" ::: "memory");
    __syncthreads();
    cur ^= 1;
    mw = mwn;
  }

  float linv = 1.0f / (lrun + __shfl_xor(lrun, 32));
  unsigned short* yrow = yb + ((long long)(b * 2048 + qglob)) * 512 + h * 64;
#pragma unroll
  for (int m = 0; m < 4; m++) {
    int d0 = 8 * m + 4 * h5;
    bf16x4 o0 = {(__bf16)(accO0[4 * m + 0] * linv), (__bf16)(accO0[4 * m + 1] * linv),
                 (__bf16)(accO0[4 * m + 2] * linv), (__bf16)(accO0[4 * m + 3] * linv)};
    bf16x4 o1 = {(__bf16)(accO1[4 * m + 0] * linv), (__bf16)(accO1[4 * m + 1] * linv),
                 (__bf16)(accO1[4 * m + 2] * linv), (__bf16)(accO1[4 * m + 3] * linv)};
    *(bf16x4*)&yrow[d0] = o0;
    *(bf16x4*)&yrow[32 + d0] = o1;
  }
}

// ---------------- launcher ----------------

extern "C" void kernel_launch(void* const* d_in, const int* in_sizes, int n_in,
                              void* d_out, int out_size, void* d_ws, size_t ws_size,
                              hipStream_t stream) {
  const float* x      = (const float*)d_in[0];
  const int*   adj    = (const int*)d_in[1];
  const float* w_qkv  = (const float*)d_in[2];
  const float* b_qkv  = (const float*)d_in[3];
  const float* w_proj = (const float*)d_in[4];
  const float* b_proj = (const float*)d_in[5];
  float* out = (float*)d_out;

  char* ws = (char*)d_ws;
  unsigned short* xb  = (unsigned short*)(ws);              // 8.4MB  (reused as yb)
  unsigned short* qb  = (unsigned short*)(ws + 8388608);    // 8.4MB
  unsigned short* kbf = (unsigned short*)(ws + 16777216);   // 8.4MB
  unsigned short* vtb = (unsigned short*)(ws + 25165824);   // 8.4MB
  unsigned short* wqt = (unsigned short*)(ws + 33554432);   // 1.57MB
  unsigned short* wpt = (unsigned short*)(ws + 35127296);   // 0.52MB
  unsigned long long* mb = (unsigned long long*)(ws + 35651584); // 2MB  (end 37.75MB)
  unsigned short* yb = xb;  // x is dead after gemm_qkv

  prep<<<dim3(21504), dim3(256), 0, stream>>>(x, xb, w_qkv, wqt, w_proj, wpt, adj, mb);
  gemm_qkv<<<dim3(64, 12), dim3(256), 0, stream>>>(xb, wqt, b_qkv, qb, kbf, vtb);
  attn<<<dim3(512), dim3(256), 0, stream>>>(qb, kbf, vtb, mb, yb);
  gemm_proj<<<dim3(64, 4), dim3(256), 0, stream>>>(yb, wpt, b_proj, out);
}